// Round 11
// baseline (79.121 us; speedup 1.0000x reference)
//
#include <hip/hip_runtime.h>
#include <hip/hip_fp16.h>

#define DIN 256
#define DOUT 128
#define KNBR 32

typedef __attribute__((ext_vector_type(4))) float f32x4;
typedef __attribute__((ext_vector_type(8))) short bf16x8;

static __device__ __forceinline__ ushort f2bf(float f) {
    uint u = __float_as_uint(f);
    return (ushort)((u + 0x7FFFu + ((u >> 16) & 1u)) >> 16);   // RNE
}

// packed f32x2 -> bf16x2 (RNE); no builtin on gfx950 -> inline asm
static __device__ __forceinline__ uint cvtpk(float lo, float hi) {
    uint r;
    asm("v_cvt_pk_bf16_f32 %0, %1, %2" : "=v"(r) : "v"(lo), "v"(hi));
    return r;
}

// One-time W fp32 -> bf16 (32768 elems)
__global__ __launch_bounds__(256) void wconv_kernel(
    const float* __restrict__ W, ushort* __restrict__ Wbf)
{
    const int idx = (blockIdx.x * 256 + threadIdx.x) * 4;
    const float4 v = *(const float4*)(W + idx);
    ushort4 o;
    o.x = f2bf(v.x); o.y = f2bf(v.y); o.z = f2bf(v.z); o.w = f2bf(v.w);
    *(ushort4*)(Wbf + idx) = o;
}

// h[n][o] = relu(feats[n][:].W[o][:] + b[o]) via bf16 MFMA, h stored fp16.
// NO LDS, NO barriers: 1 wave per 64-thr block, wave = 32 rows x 128 cols.
// A-fragments stream global->VGPR (each row used by exactly one wave; LDS
// staging bought nothing and cost a wait-chain per chunk -- 6 prior variants
// all pinned at ~26 us). B streams from L2-resident Wbf. Fully-unrolled K
// loop lets the compiler software-pipeline the independent loads.
__global__ __launch_bounds__(64) void fc_mfma_kernel(
    const float* __restrict__ feats, const ushort* __restrict__ Wbf,
    const float* __restrict__ bias, __half* __restrict__ h, int N)
{
    const int lane = threadIdx.x;              // 0..63
    const int l15  = lane & 15, lq = lane >> 4;
    const int r0   = blockIdx.x * 32;

    // clamped global row per mi (tail block)
    int grow[2];
    #pragma unroll
    for (int mi = 0; mi < 2; ++mi) {
        int g = r0 + mi * 16 + l15;
        grow[mi] = (g > N - 1) ? (N - 1) : g;
    }

    f32x4 acc[2][8];
    #pragma unroll
    for (int mi = 0; mi < 2; ++mi)
        #pragma unroll
        for (int ni = 0; ni < 8; ++ni) acc[mi][ni] = (f32x4){0.f, 0.f, 0.f, 0.f};

    #pragma unroll
    for (int kc = 0; kc < 4; ++kc) {           // K-chunks of 64
        // ---- A: 8 x 16 B global loads -> cvt -> a[mi][j] ----
        bf16x8 a[2][2];
        #pragma unroll
        for (int mi = 0; mi < 2; ++mi) {
            const float* arow = feats + (size_t)grow[mi] * DIN + kc * 64 + lq * 8;
            #pragma unroll
            for (int j = 0; j < 2; ++j) {
                const f32x4 lo = *(const f32x4*)(arow + j * 32);
                const f32x4 hi = *(const f32x4*)(arow + j * 32 + 4);
                uint4 u;
                u.x = cvtpk(lo.x, lo.y); u.y = cvtpk(lo.z, lo.w);
                u.z = cvtpk(hi.x, hi.y); u.w = cvtpk(hi.z, hi.w);
                union { uint4 q; bf16x8 v; } cv; cv.q = u;
                a[mi][j] = cv.v;
            }
        }
        // ---- B per j from L2 + 32 MFMAs ----
        #pragma unroll
        for (int j = 0; j < 2; ++j) {
            bf16x8 breg[8];
            #pragma unroll
            for (int ni = 0; ni < 8; ++ni)
                breg[ni] = *(const bf16x8*)(
                    Wbf + (size_t)(ni * 16 + l15) * DIN + kc * 64 + j * 32 + lq * 8);
            #pragma unroll
            for (int mi = 0; mi < 2; ++mi)
                #pragma unroll
                for (int ni = 0; ni < 8; ++ni)
                    acc[mi][ni] = __builtin_amdgcn_mfma_f32_16x16x32_bf16(
                        a[mi][j], breg[ni], acc[mi][ni], 0, 0, 0);
        }
    }

    // ---- epilogue: bias + relu -> fp16 h ----
    float bcol[8];
    #pragma unroll
    for (int ni = 0; ni < 8; ++ni) bcol[ni] = bias[ni * 16 + l15];

    #pragma unroll
    for (int mi = 0; mi < 2; ++mi) {
        const int rbase = r0 + mi * 16 + lq * 4;
        #pragma unroll
        for (int ni = 0; ni < 8; ++ni) {
            const int col = ni * 16 + l15;
            #pragma unroll
            for (int r = 0; r < 4; ++r) {
                const int n = rbase + r;
                if (n < N) {
                    const float v = fmaxf(acc[mi][ni][r] + bcol[ni], 0.f);
                    h[(size_t)n * DOUT + col] = __float2half_rn(v);
                }
            }
        }
    }
}

// pooled[n][:] = mean_k h[edge[n][k]][:]
// 16 nodes / 256-thr block, 16 lanes per node, 16 B (Half8) per lane.
// MLP probe: explicit 16-deep load batches (v[16] live simultaneously ->
// compiler must issue 16 gathers before first consume; previous VGPR=40
// build only kept ~6 in flight).
struct __align__(16) Half8 { __half2 a, b, c, d; };

__global__ __launch_bounds__(256) void pool_kernel(
    const __half* __restrict__ h, const int* __restrict__ edge,
    float* __restrict__ out, int N)
{
    __shared__ int eLds[16 * KNBR];            // 2 KB

    const int tid = threadIdx.x;
    const int g   = tid >> 4;                  // node group 0..15
    const int l   = tid & 15;
    const int nb  = blockIdx.x * 16;

    const int* esrc = edge + (size_t)nb * KNBR;
    eLds[tid]       = esrc[tid];
    eLds[tid + 256] = esrc[tid + 256];
    __syncthreads();

    const Half8* h8 = (const Half8*)h;         // row stride = DOUT/8 = 16
    const int* el = &eLds[g * KNBR];

    float4 acc0 = {0.f, 0.f, 0.f, 0.f};
    float4 acc1 = {0.f, 0.f, 0.f, 0.f};

    #pragma unroll
    for (int b = 0; b < 2; ++b) {
        Half8 v[16];
        #pragma unroll
        for (int k = 0; k < 16; ++k)
            v[k] = h8[(size_t)el[b * 16 + k] * (DOUT / 8) + l];
        #pragma unroll
        for (int k = 0; k < 16; ++k) {
            const float2 f0 = __half22float2(v[k].a);
            const float2 f1 = __half22float2(v[k].b);
            const float2 f2 = __half22float2(v[k].c);
            const float2 f3 = __half22float2(v[k].d);
            acc0.x += f0.x; acc0.y += f0.y; acc0.z += f1.x; acc0.w += f1.y;
            acc1.x += f2.x; acc1.y += f2.y; acc1.z += f3.x; acc1.w += f3.y;
        }
    }

    const float s = 1.0f / (float)KNBR;
    float4 r0, r1;
    r0.x = acc0.x * s; r0.y = acc0.y * s; r0.z = acc0.z * s; r0.w = acc0.w * s;
    r1.x = acc1.x * s; r1.y = acc1.y * s; r1.z = acc1.z * s; r1.w = acc1.w * s;

    const int node = nb + g;
    float4* op = (float4*)(out + (size_t)node * DOUT + l * 8);
    op[0] = r0; op[1] = r1;
}

extern "C" void kernel_launch(void* const* d_in, const int* in_sizes, int n_in,
                              void* d_out, int out_size, void* d_ws, size_t ws_size,
                              hipStream_t stream) {
    // dict order: ids, feats, W, b, edge_dict, G, ite
    const float* feats = (const float*)d_in[1];
    const float* W     = (const float*)d_in[2];
    const float* bias  = (const float*)d_in[3];
    const int*   edge  = (const int*)d_in[4];
    float* out = (float*)d_out;

    const int N = in_sizes[1] / DIN;            // 50000
    __half* h   = (__half*)d_ws;                // N*DOUT*2 = 12.8 MB
    ushort* Wbf = (ushort*)((char*)d_ws + (size_t)N * DOUT * sizeof(__half));

    wconv_kernel<<<(DOUT * DIN) / 1024, 256, 0, stream>>>(W, Wbf);
    fc_mfma_kernel<<<(N + 31) / 32, 64, 0, stream>>>(feats, Wbf, bias, h, N);
    pool_kernel<<<N / 16, 256, 0, stream>>>(h, edge, out, N);
}

// Round 12
// 78.005 us; speedup vs baseline: 1.0143x; 1.0143x over previous
//
#include <hip/hip_runtime.h>
#include <hip/hip_fp16.h>

#define DIN 256
#define DOUT 128
#define KNBR 32
#define MT 224        // grid = ceil(50000/224) = 224 blocks <= 256 CUs: depth-1 dispatch
#define KCH 128       // K-chunk: 224 rows x 128 fp32 = 114.7 KB LDS, 2 chunks

typedef __attribute__((ext_vector_type(4))) float f32x4;
typedef __attribute__((ext_vector_type(8))) short bf16x8;

static __device__ __forceinline__ ushort f2bf(float f) {
    uint u = __float_as_uint(f);
    return (ushort)((u + 0x7FFFu + ((u >> 16) & 1u)) >> 16);   // RNE
}

// packed f32x2 -> bf16x2 (RNE); no builtin on gfx950 -> inline asm
static __device__ __forceinline__ uint cvtpk(float lo, float hi) {
    uint r;
    asm("v_cvt_pk_bf16_f32 %0, %1, %2" : "=v"(r) : "v"(lo), "v"(hi));
    return r;
}

// async global->LDS DMA, 16 B/lane, LDS dest = wave-uniform base + lane*16
static __device__ __forceinline__ void gload_lds16(const float* g, void* l) {
    __builtin_amdgcn_global_load_lds(
        (const __attribute__((address_space(1))) void*)g,
        (__attribute__((address_space(3))) void*)l,
        16, 0, 0);
}

// One-time W fp32 -> bf16 (32768 elems)
__global__ __launch_bounds__(256) void wconv_kernel(
    const float* __restrict__ W, ushort* __restrict__ Wbf)
{
    const int idx = (blockIdx.x * 256 + threadIdx.x) * 4;
    const float4 v = *(const float4*)(W + idx);
    ushort4 o;
    o.x = f2bf(v.x); o.y = f2bf(v.y); o.z = f2bf(v.z); o.w = f2bf(v.w);
    *(ushort4*)(Wbf + idx) = o;
}

// h[n][o] = relu(feats[n][:].W[o][:] + b[o]) via bf16 MFMA, h stored fp16.
// MT=224: grid 224 -> every CU gets at most ONE block (serial depth 1; the
// 2-deep tail at grid 391 was the invariant across six ~26 us variants).
// KCH=128: 2 chunks, 2 DMA drains. B for the whole chunk preloaded right
// after the stage issues -> lands during the drain. Wave = 112 rows x 64 cols
// (acc[7][4]). A staged fp32 via global_load_lds, source pre-XOR-swizzled.
__global__ __launch_bounds__(256) void fc_mfma_kernel(
    const float* __restrict__ feats, const ushort* __restrict__ Wbf,
    const float* __restrict__ bias, __half* __restrict__ h, int N)
{
    __shared__ float lds_a[MT * KCH];   // 114688 B
    char* lds = (char*)lds_a;

    const int tid  = threadIdx.x;
    const int lane = tid & 63;
    const int wv   = tid >> 6;
    const int wm   = wv >> 1, wn = wv & 1;   // row-half / col-half
    const int l15  = lane & 15, lq = lane >> 4;
    const int nb   = blockIdx.x * MT;

    f32x4 acc[7][4];
    #pragma unroll
    for (int mi = 0; mi < 7; ++mi)
        #pragma unroll
        for (int ni = 0; ni < 4; ++ni) acc[mi][ni] = (f32x4){0.f, 0.f, 0.f, 0.f};

    #pragma unroll
    for (int kc = 0; kc < 2; ++kc) {
        if (kc) __syncthreads();   // chunk-0 reads complete before overwrite

        // ---- stage: 28 DMA issues/wave, each 1 KB = 2 rows x 512 B ----
        // row stride 512 B; source 16B-unit index pre-XORed with (row&7) so
        // the linear LDS ends up swizzled (G4/m173).
        #pragma unroll
        for (int it = 0; it < 28; ++it) {
            const int row = wv * 56 + it * 2 + (lane >> 5);
            const int c4  = (lane & 31) ^ (row & 7);
            int grow = nb + row; if (grow > N - 1) grow = N - 1;
            const float* src = feats + (size_t)grow * DIN + kc * KCH + c4 * 4;
            gload_lds16(src, lds + (wv * 56 + it * 2) * 512);
        }

        // ---- preload ALL B fragments for this chunk (lands during drain) ----
        bf16x8 breg[4][4];   // [j][ni], 64 VGPR
        #pragma unroll
        for (int j = 0; j < 4; ++j)
            #pragma unroll
            for (int ni = 0; ni < 4; ++ni)
                breg[j][ni] = *(const bf16x8*)(
                    Wbf + (size_t)(wn * 64 + ni * 16 + l15) * DIN
                        + kc * KCH + j * 32 + lq * 8);

        __syncthreads();   // drain DMA (vmcnt(0) + barrier)

        // ---- compute: 4 K-steps of 32 ----
        #pragma unroll
        for (int j = 0; j < 4; ++j) {
            bf16x8 a[7];
            #pragma unroll
            for (int mi = 0; mi < 7; ++mi) {
                const int row = wm * 112 + mi * 16 + l15;
                const int X = (row & 7) << 4;
                const int b0 = row * 512 + j * 128 + lq * 32;
                const f32x4 lo = *(const f32x4*)(lds + ((b0) ^ X));
                const f32x4 hi = *(const f32x4*)(lds + ((b0 + 16) ^ X));
                uint4 u;
                u.x = cvtpk(lo.x, lo.y); u.y = cvtpk(lo.z, lo.w);
                u.z = cvtpk(hi.x, hi.y); u.w = cvtpk(hi.z, hi.w);
                union { uint4 q; bf16x8 v; } cv; cv.q = u;
                a[mi] = cv.v;
            }
            #pragma unroll
            for (int mi = 0; mi < 7; ++mi)
                #pragma unroll
                for (int ni = 0; ni < 4; ++ni)
                    acc[mi][ni] = __builtin_amdgcn_mfma_f32_16x16x32_bf16(
                        a[mi], breg[j][ni], acc[mi][ni], 0, 0, 0);
        }
    }

    // ---- epilogue: bias + relu -> fp16 h ----
    float bcol[4];
    #pragma unroll
    for (int ni = 0; ni < 4; ++ni) bcol[ni] = bias[wn * 64 + ni * 16 + l15];

    #pragma unroll
    for (int mi = 0; mi < 7; ++mi) {
        const int rbase = nb + wm * 112 + mi * 16 + lq * 4;
        #pragma unroll
        for (int ni = 0; ni < 4; ++ni) {
            const int col = wn * 64 + ni * 16 + l15;
            #pragma unroll
            for (int r = 0; r < 4; ++r) {
                const int n = rbase + r;
                if (n < N) {
                    const float v = fmaxf(acc[mi][ni][r] + bcol[ni], 0.f);
                    h[(size_t)n * DOUT + col] = __float2half_rn(v);
                }
            }
        }
    }
}

// pooled[n][:] = mean_k h[edge[n][k]][:]
// 16 nodes / 256-thr block, 16 lanes per node, 16 B (Half8) per lane, 16-deep
// explicit load batches. At its structural floor (~45.5 us): seven variants
// (blast/sorted/paced/sliced/8B/16B/16-deep) within +-2 us; FETCH varied
// 118-176 MB with no time response -> L2/fabric random-access capacity bound.
struct __align__(16) Half8 { __half2 a, b, c, d; };

__global__ __launch_bounds__(256) void pool_kernel(
    const __half* __restrict__ h, const int* __restrict__ edge,
    float* __restrict__ out, int N)
{
    __shared__ int eLds[16 * KNBR];            // 2 KB

    const int tid = threadIdx.x;
    const int g   = tid >> 4;                  // node group 0..15
    const int l   = tid & 15;
    const int nb  = blockIdx.x * 16;

    const int* esrc = edge + (size_t)nb * KNBR;
    eLds[tid]       = esrc[tid];
    eLds[tid + 256] = esrc[tid + 256];
    __syncthreads();

    const Half8* h8 = (const Half8*)h;         // row stride = DOUT/8 = 16
    const int* el = &eLds[g * KNBR];

    float4 acc0 = {0.f, 0.f, 0.f, 0.f};
    float4 acc1 = {0.f, 0.f, 0.f, 0.f};

    #pragma unroll
    for (int b = 0; b < 2; ++b) {
        Half8 v[16];
        #pragma unroll
        for (int k = 0; k < 16; ++k)
            v[k] = h8[(size_t)el[b * 16 + k] * (DOUT / 8) + l];
        #pragma unroll
        for (int k = 0; k < 16; ++k) {
            const float2 f0 = __half22float2(v[k].a);
            const float2 f1 = __half22float2(v[k].b);
            const float2 f2 = __half22float2(v[k].c);
            const float2 f3 = __half22float2(v[k].d);
            acc0.x += f0.x; acc0.y += f0.y; acc0.z += f1.x; acc0.w += f1.y;
            acc1.x += f2.x; acc1.y += f2.y; acc1.z += f3.x; acc1.w += f3.y;
        }
    }

    const float s = 1.0f / (float)KNBR;
    float4 r0, r1;
    r0.x = acc0.x * s; r0.y = acc0.y * s; r0.z = acc0.z * s; r0.w = acc0.w * s;
    r1.x = acc1.x * s; r1.y = acc1.y * s; r1.z = acc1.z * s; r1.w = acc1.w * s;

    const int node = nb + g;
    float4* op = (float4*)(out + (size_t)node * DOUT + l * 8);
    op[0] = r0; op[1] = r1;
}

extern "C" void kernel_launch(void* const* d_in, const int* in_sizes, int n_in,
                              void* d_out, int out_size, void* d_ws, size_t ws_size,
                              hipStream_t stream) {
    // dict order: ids, feats, W, b, edge_dict, G, ite
    const float* feats = (const float*)d_in[1];
    const float* W     = (const float*)d_in[2];
    const float* bias  = (const float*)d_in[3];
    const int*   edge  = (const int*)d_in[4];
    float* out = (float*)d_out;

    const int N = in_sizes[1] / DIN;            // 50000
    __half* h   = (__half*)d_ws;                // N*DOUT*2 = 12.8 MB
    ushort* Wbf = (ushort*)((char*)d_ws + (size_t)N * DOUT * sizeof(__half));

    wconv_kernel<<<(DOUT * DIN) / 1024, 256, 0, stream>>>(W, Wbf);
    fc_mfma_kernel<<<(N + MT - 1) / MT, 256, 0, stream>>>(feats, Wbf, bias, h, N);
    pool_kernel<<<N / 16, 256, 0, stream>>>(h, edge, out, N);
}

// Round 13
// 75.809 us; speedup vs baseline: 1.0437x; 1.0290x over previous
//
#include <hip/hip_runtime.h>
#include <hip/hip_fp16.h>

#define DIN 256
#define DOUT 128
#define KNBR 32
#define MT 128        // M-tile rows per FC block; grid 391, 2 blocks/CU -> all co-resident

typedef __attribute__((ext_vector_type(4))) float f32x4;
typedef __attribute__((ext_vector_type(8))) short bf16x8;

// packed f32x2 -> bf16x2 (RNE); no builtin on gfx950 -> inline asm
static __device__ __forceinline__ uint cvtpk(float lo, float hi) {
    uint r;
    asm("v_cvt_pk_bf16_f32 %0, %1, %2" : "=v"(r) : "v"(lo), "v"(hi));
    return r;
}

static __device__ __forceinline__ bf16x8 cvt8(const f32x4 lo, const f32x4 hi) {
    uint4 u;
    u.x = cvtpk(lo.x, lo.y); u.y = cvtpk(lo.z, lo.w);
    u.z = cvtpk(hi.x, hi.y); u.w = cvtpk(hi.z, hi.w);
    union { uint4 q; bf16x8 v; } cv; cv.q = u;
    return cv.v;
}

// h[n][o] = relu(feats[n][:].W[o][:] + b[o]) via bf16 MFMA, h stored fp16.
// Fixes vs all prior ~26us variants:
//  (1) reg-staged single 64KB bf16 A-tile (whole K): 32 independent coalesced
//      float4 loads/thread pipelined by the compiler, cvt_pk once at stage
//      time, ds_write_b128, ONE barrier; K-loop is pure ds_read+MFMA.
//  (2) XOR-swizzle on LDS write AND read (round-2's killer was the unswizzled
//      16-way read conflict, not reg-staging itself).
//  (3) coalesced h-write: out-tile staged in (reused) LDS, read back linear,
//      16B global stores (old epilogue was a 2B scatter -> L2 RMW).
//  (4) W converted in-kernel from fp32 (L2-resident) -> no wconv launch.
__global__ __launch_bounds__(256) void fc_mfma_kernel(
    const float* __restrict__ feats, const float* __restrict__ W,
    const float* __restrict__ bias, __half* __restrict__ h, int N)
{
    __shared__ char lds[MT * DIN * 2];   // 64 KB: bf16 A-tile, then out-tile
    const int tid  = threadIdx.x;
    const int lane = tid & 63;
    const int wv   = tid >> 6;
    const int wm   = wv >> 1, wn = wv & 1;
    const int l15  = lane & 15, lq = lane >> 4;
    const int nb   = blockIdx.x * MT;

    // ---- stage A: 128 rows x 32 units (16B bf16 = 8 cols); 16 units/thread ----
    #pragma unroll
    for (int i = 0; i < 16; ++i) {
        const int u    = i * 256 + tid;
        const int row  = u >> 5;
        const int unit = u & 31;
        int grow = nb + row; if (grow > N - 1) grow = N - 1;
        const float* src = feats + (size_t)grow * DIN + unit * 8;
        const f32x4 lo = *(const f32x4*)(src);
        const f32x4 hi = *(const f32x4*)(src + 4);
        *(bf16x8*)(lds + row * 512 + (unit ^ (row & 7)) * 16) = cvt8(lo, hi);
    }
    __syncthreads();

    // ---- K loop: pure ds_read + MFMA; B streamed from L2-resident fp32 W ----
    f32x4 acc[4][4];
    #pragma unroll
    for (int mi = 0; mi < 4; ++mi)
        #pragma unroll
        for (int ni = 0; ni < 4; ++ni) acc[mi][ni] = (f32x4){0.f, 0.f, 0.f, 0.f};

    #pragma unroll
    for (int ks = 0; ks < 8; ++ks) {
        bf16x8 breg[4];
        #pragma unroll
        for (int ni = 0; ni < 4; ++ni) {
            const float* wr = W + (size_t)(wn * 64 + ni * 16 + l15) * DIN
                                + ks * 32 + lq * 8;
            breg[ni] = cvt8(*(const f32x4*)wr, *(const f32x4*)(wr + 4));
        }
        bf16x8 a[4];
        #pragma unroll
        for (int mi = 0; mi < 4; ++mi) {
            const int row = wm * 64 + mi * 16 + l15;
            a[mi] = *(const bf16x8*)(
                lds + row * 512 + ((ks * 4 + lq) ^ (row & 7)) * 16);
        }
        #pragma unroll
        for (int mi = 0; mi < 4; ++mi)
            #pragma unroll
            for (int ni = 0; ni < 4; ++ni)
                acc[mi][ni] = __builtin_amdgcn_mfma_f32_16x16x32_bf16(
                    a[mi], breg[ni], acc[mi][ni], 0, 0, 0);
    }

    // ---- epilogue: bias+relu -> fp16 out-tile in LDS -> coalesced 16B stores ----
    float bcol[4];
    #pragma unroll
    for (int ni = 0; ni < 4; ++ni) bcol[ni] = bias[wn * 64 + ni * 16 + l15];

    __syncthreads();   // A-tile reads done; reuse LDS for out-tile (32 KB)
    #pragma unroll
    for (int mi = 0; mi < 4; ++mi) {
        const int lrow0 = wm * 64 + mi * 16 + lq * 4;
        #pragma unroll
        for (int ni = 0; ni < 4; ++ni) {
            const int col = wn * 64 + ni * 16 + l15;
            #pragma unroll
            for (int r = 0; r < 4; ++r) {
                const float v = fmaxf(acc[mi][ni][r] + bcol[ni], 0.f);
                *(ushort*)(lds + (lrow0 + r) * 256 + col * 2) =
                    __half_as_ushort(__float2half_rn(v));
            }
        }
    }
    __syncthreads();

    // read back linear: thread t -> row t>>1, half-row t&1 (128 B = 8 x 16 B)
    {
        const int lrow = tid >> 1, seg = tid & 1;
        const int grow = nb + lrow;
        if (grow < N) {
            ushort* dst = (ushort*)h + (size_t)grow * DOUT + seg * 64;
            #pragma unroll
            for (int i = 0; i < 8; ++i)
                *(bf16x8*)(dst + i * 8) =
                    *(const bf16x8*)(lds + lrow * 256 + seg * 128 + i * 16);
        }
    }
}

// pooled[n][:] = mean_k h[edge[n][k]][:]
// 16 nodes / 256-thr block, 16 lanes per node, 16 B (Half8) per lane, 16-deep
// batches. At structural floor (~45.5 us): eight variants within +-2 us;
// FETCH varied 118-176 MB with no time response -> L3/fabric random-access
// capacity bound (MSHR-limited latency), not hit-rate or MLP limited.
struct __align__(16) Half8 { __half2 a, b, c, d; };

__global__ __launch_bounds__(256) void pool_kernel(
    const __half* __restrict__ h, const int* __restrict__ edge,
    float* __restrict__ out, int N)
{
    __shared__ int eLds[16 * KNBR];            // 2 KB

    const int tid = threadIdx.x;
    const int g   = tid >> 4;                  // node group 0..15
    const int l   = tid & 15;
    const int nb  = blockIdx.x * 16;

    const int* esrc = edge + (size_t)nb * KNBR;
    eLds[tid]       = esrc[tid];
    eLds[tid + 256] = esrc[tid + 256];
    __syncthreads();

    const Half8* h8 = (const Half8*)h;         // row stride = DOUT/8 = 16
    const int* el = &eLds[g * KNBR];

    float4 acc0 = {0.f, 0.f, 0.f, 0.f};
    float4 acc1 = {0.f, 0.f, 0.f, 0.f};

    #pragma unroll
    for (int b = 0; b < 2; ++b) {
        Half8 v[16];
        #pragma unroll
        for (int k = 0; k < 16; ++k)
            v[k] = h8[(size_t)el[b * 16 + k] * (DOUT / 8) + l];
        #pragma unroll
        for (int k = 0; k < 16; ++k) {
            const float2 f0 = __half22float2(v[k].a);
            const float2 f1 = __half22float2(v[k].b);
            const float2 f2 = __half22float2(v[k].c);
            const float2 f3 = __half22float2(v[k].d);
            acc0.x += f0.x; acc0.y += f0.y; acc0.z += f1.x; acc0.w += f1.y;
            acc1.x += f2.x; acc1.y += f2.y; acc1.z += f3.x; acc1.w += f3.y;
        }
    }

    const float s = 1.0f / (float)KNBR;
    float4 r0, r1;
    r0.x = acc0.x * s; r0.y = acc0.y * s; r0.z = acc0.z * s; r0.w = acc0.w * s;
    r1.x = acc1.x * s; r1.y = acc1.y * s; r1.z = acc1.z * s; r1.w = acc1.w * s;

    const int node = nb + g;
    float4* op = (float4*)(out + (size_t)node * DOUT + l * 8);
    op[0] = r0; op[1] = r1;
}

extern "C" void kernel_launch(void* const* d_in, const int* in_sizes, int n_in,
                              void* d_out, int out_size, void* d_ws, size_t ws_size,
                              hipStream_t stream) {
    // dict order: ids, feats, W, b, edge_dict, G, ite
    const float* feats = (const float*)d_in[1];
    const float* W     = (const float*)d_in[2];
    const float* bias  = (const float*)d_in[3];
    const int*   edge  = (const int*)d_in[4];
    float* out = (float*)d_out;

    const int N = in_sizes[1] / DIN;            // 50000
    __half* h   = (__half*)d_ws;                // N*DOUT*2 = 12.8 MB

    fc_mfma_kernel<<<(N + MT - 1) / MT, 256, 0, stream>>>(feats, W, bias, h, N);
    pool_kernel<<<N / 16, 256, 0, stream>>>(h, edge, out, N);
}

// Round 14
// 68.398 us; speedup vs baseline: 1.1568x; 1.1083x over previous
//
#include <hip/hip_runtime.h>
#include <hip/hip_fp16.h>

#define DIN 256
#define DOUT 128
#define KNBR 32
#define MT 128        // M-tile rows per FC block; grid 391

typedef __attribute__((ext_vector_type(4))) float f32x4;
typedef __attribute__((ext_vector_type(8))) short bf16x8;

// packed f32x2 -> bf16x2 (RNE); no builtin on gfx950 -> inline asm
static __device__ __forceinline__ uint cvtpk(float lo, float hi) {
    uint r;
    asm("v_cvt_pk_bf16_f32 %0, %1, %2" : "=v"(r) : "v"(lo), "v"(hi));
    return r;
}

static __device__ __forceinline__ bf16x8 cvt8(const f32x4 lo, const f32x4 hi) {
    uint4 u;
    u.x = cvtpk(lo.x, lo.y); u.y = cvtpk(lo.z, lo.w);
    u.z = cvtpk(hi.x, hi.y); u.w = cvtpk(hi.z, hi.w);
    union { uint4 q; bf16x8 v; } cv; cv.q = u;
    return cv.v;
}

// h[n][o] = relu(feats[n][:].W[o][:] + b[o]) via bf16 MFMA.
// h stored as TWO fp16 column-planes [2][N][64] so the pool can process a
// 6.4 MB working set per pass (L2 hit-rate lever).
__global__ __launch_bounds__(256) void fc_mfma_kernel(
    const float* __restrict__ feats, const float* __restrict__ W,
    const float* __restrict__ bias, __half* __restrict__ h, int N)
{
    __shared__ char lds[MT * DIN * 2];   // 64 KB: bf16 A-tile, then out-tile
    const int tid  = threadIdx.x;
    const int lane = tid & 63;
    const int wv   = tid >> 6;
    const int wm   = wv >> 1, wn = wv & 1;
    const int l15  = lane & 15, lq = lane >> 4;
    const int nb   = blockIdx.x * MT;

    // ---- stage A: 128 rows x 32 units (16B bf16 = 8 cols); 16 units/thread ----
    #pragma unroll
    for (int i = 0; i < 16; ++i) {
        const int u    = i * 256 + tid;
        const int row  = u >> 5;
        const int unit = u & 31;
        int grow = nb + row; if (grow > N - 1) grow = N - 1;
        const float* src = feats + (size_t)grow * DIN + unit * 8;
        const f32x4 lo = *(const f32x4*)(src);
        const f32x4 hi = *(const f32x4*)(src + 4);
        *(bf16x8*)(lds + row * 512 + (unit ^ (row & 7)) * 16) = cvt8(lo, hi);
    }
    __syncthreads();

    // ---- K loop: pure ds_read + MFMA; B from L2-resident fp32 W (cvt in reg) ----
    f32x4 acc[4][4];
    #pragma unroll
    for (int mi = 0; mi < 4; ++mi)
        #pragma unroll
        for (int ni = 0; ni < 4; ++ni) acc[mi][ni] = (f32x4){0.f, 0.f, 0.f, 0.f};

    #pragma unroll
    for (int ks = 0; ks < 8; ++ks) {
        bf16x8 breg[4];
        #pragma unroll
        for (int ni = 0; ni < 4; ++ni) {
            const float* wr = W + (size_t)(wn * 64 + ni * 16 + l15) * DIN
                                + ks * 32 + lq * 8;
            breg[ni] = cvt8(*(const f32x4*)wr, *(const f32x4*)(wr + 4));
        }
        bf16x8 a[4];
        #pragma unroll
        for (int mi = 0; mi < 4; ++mi) {
            const int row = wm * 64 + mi * 16 + l15;
            a[mi] = *(const bf16x8*)(
                lds + row * 512 + ((ks * 4 + lq) ^ (row & 7)) * 16);
        }
        #pragma unroll
        for (int mi = 0; mi < 4; ++mi)
            #pragma unroll
            for (int ni = 0; ni < 4; ++ni)
                acc[mi][ni] = __builtin_amdgcn_mfma_f32_16x16x32_bf16(
                    a[mi], breg[ni], acc[mi][ni], 0, 0, 0);
    }

    // ---- epilogue: bias+relu -> fp16 out-tile in LDS -> coalesced 16B stores ----
    float bcol[4];
    #pragma unroll
    for (int ni = 0; ni < 4; ++ni) bcol[ni] = bias[wn * 64 + ni * 16 + l15];

    __syncthreads();   // A-tile reads done; reuse LDS for out-tile (32 KB)
    #pragma unroll
    for (int mi = 0; mi < 4; ++mi) {
        const int lrow0 = wm * 64 + mi * 16 + lq * 4;
        #pragma unroll
        for (int ni = 0; ni < 4; ++ni) {
            const int col = wn * 64 + ni * 16 + l15;
            #pragma unroll
            for (int r = 0; r < 4; ++r) {
                const float v = fmaxf(acc[mi][ni][r] + bcol[ni], 0.f);
                *(ushort*)(lds + (lrow0 + r) * 256 + col * 2) =
                    __half_as_ushort(__float2half_rn(v));
            }
        }
    }
    __syncthreads();

    // read back: thread t -> row t>>1, plane t&1; 128 B -> plane (t&1)
    {
        const int lrow = tid >> 1, p = tid & 1;
        const int grow = nb + lrow;
        if (grow < N) {
            ushort* dst = (ushort*)h + (size_t)p * N * 64 + (size_t)grow * 64;
            #pragma unroll
            for (int i = 0; i < 8; ++i)
                *(bf16x8*)(dst + i * 8) =
                    *(const bf16x8*)(lds + lrow * 256 + p * 128 + i * 16);
        }
    }
}

// pooled[n][p*64..+63] = mean_k hplane_p[edge[n][k]][:]
// One pass per 6.4 MB plane (two stream-serialized launches) -> concurrent
// gather working set halves; 8 lanes/node x 16 B = 128 B = exactly one L2
// line per gathered row (no sub-line over-fetch).
struct __align__(16) Half8 { __half2 a, b, c, d; };

__global__ __launch_bounds__(256) void pool_kernel(
    const __half* __restrict__ h, const int* __restrict__ edge,
    float* __restrict__ out, int N, int p)
{
    __shared__ int eLds[32 * KNBR];            // 4 KB

    const int tid = threadIdx.x;
    const int g   = tid >> 3;                  // node group 0..31
    const int l   = tid & 7;
    const int nb  = blockIdx.x * 32;

    // stage this block's 1024 edge indices (coalesced, guarded)
    const int* esrc = edge + (size_t)nb * KNBR;
    const int limit = (N - nb) * KNBR;         // valid edge count in block
    #pragma unroll
    for (int i = 0; i < 4; ++i) {
        const int ei = tid + i * 256;
        eLds[ei] = (ei < limit) ? esrc[ei] : 0;
    }
    __syncthreads();

    const int node = nb + g;
    if (node >= N) return;

    const Half8* plane = (const Half8*)((const ushort*)h + (size_t)p * N * 64);
    const int* el = &eLds[g * KNBR];           // row stride = 64 halfs = 8 Half8

    float4 acc0 = {0.f, 0.f, 0.f, 0.f};
    float4 acc1 = {0.f, 0.f, 0.f, 0.f};

    #pragma unroll
    for (int b = 0; b < 2; ++b) {
        Half8 v[16];
        #pragma unroll
        for (int k = 0; k < 16; ++k)
            v[k] = plane[(size_t)el[b * 16 + k] * 8 + l];
        #pragma unroll
        for (int k = 0; k < 16; ++k) {
            const float2 f0 = __half22float2(v[k].a);
            const float2 f1 = __half22float2(v[k].b);
            const float2 f2 = __half22float2(v[k].c);
            const float2 f3 = __half22float2(v[k].d);
            acc0.x += f0.x; acc0.y += f0.y; acc0.z += f1.x; acc0.w += f1.y;
            acc1.x += f2.x; acc1.y += f2.y; acc1.z += f3.x; acc1.w += f3.y;
        }
    }

    const float s = 1.0f / (float)KNBR;
    float4 r0, r1;
    r0.x = acc0.x * s; r0.y = acc0.y * s; r0.z = acc0.z * s; r0.w = acc0.w * s;
    r1.x = acc1.x * s; r1.y = acc1.y * s; r1.z = acc1.z * s; r1.w = acc1.w * s;

    float4* op = (float4*)(out + (size_t)node * DOUT + p * 64 + l * 8);
    op[0] = r0; op[1] = r1;
}

extern "C" void kernel_launch(void* const* d_in, const int* in_sizes, int n_in,
                              void* d_out, int out_size, void* d_ws, size_t ws_size,
                              hipStream_t stream) {
    // dict order: ids, feats, W, b, edge_dict, G, ite
    const float* feats = (const float*)d_in[1];
    const float* W     = (const float*)d_in[2];
    const float* bias  = (const float*)d_in[3];
    const int*   edge  = (const int*)d_in[4];
    float* out = (float*)d_out;

    const int N = in_sizes[1] / DIN;            // 50000
    __half* h   = (__half*)d_ws;                // 2 planes x N x 64 fp16 = 12.8 MB

    fc_mfma_kernel<<<(N + MT - 1) / MT, 256, 0, stream>>>(feats, W, bias, h, N);
    const int pblocks = (N + 31) / 32;          // 1563
    pool_kernel<<<pblocks, 256, 0, stream>>>(h, edge, out, N, 0);
    pool_kernel<<<pblocks, 256, 0, stream>>>(h, edge, out, N, 1);
}

// Round 15
// 68.092 us; speedup vs baseline: 1.1620x; 1.0045x over previous
//
#include <hip/hip_runtime.h>
#include <hip/hip_fp16.h>

#define DIN 256
#define DOUT 128
#define KNBR 32
#define MT 128        // M-tile rows; grid 391, 64 KB LDS -> 2 blocks/CU, all co-resident
#define KCH 128       // K-chunk: 128 rows x 128 fp32 = 64 KB, 2 chunks

typedef __attribute__((ext_vector_type(4))) float f32x4;
typedef __attribute__((ext_vector_type(8))) short bf16x8;

static __device__ __forceinline__ ushort f2bf(float f) {
    uint u = __float_as_uint(f);
    return (ushort)((u + 0x7FFFu + ((u >> 16) & 1u)) >> 16);   // RNE
}

// packed f32x2 -> bf16x2 (RNE); no builtin on gfx950 -> inline asm
static __device__ __forceinline__ uint cvtpk(float lo, float hi) {
    uint r;
    asm("v_cvt_pk_bf16_f32 %0, %1, %2" : "=v"(r) : "v"(lo), "v"(hi));
    return r;
}

static __device__ __forceinline__ bf16x8 cvt8(const f32x4 lo, const f32x4 hi) {
    uint4 u;
    u.x = cvtpk(lo.x, lo.y); u.y = cvtpk(lo.z, lo.w);
    u.z = cvtpk(hi.x, hi.y); u.w = cvtpk(hi.z, hi.w);
    union { uint4 q; bf16x8 v; } cv; cv.q = u;
    return cv.v;
}

// async global->LDS DMA, 16 B/lane, LDS dest = wave-uniform base + lane*16
static __device__ __forceinline__ void gload_lds16(const float* g, void* l) {
    __builtin_amdgcn_global_load_lds(
        (const __attribute__((address_space(1))) void*)g,
        (__attribute__((address_space(3))) void*)l,
        16, 0, 0);
}

// One-time W fp32 -> bf16 (32768 elems)
__global__ __launch_bounds__(256) void wconv_kernel(
    const float* __restrict__ W, ushort* __restrict__ Wbf)
{
    const int idx = (blockIdx.x * 256 + threadIdx.x) * 4;
    const float4 v = *(const float4*)(W + idx);
    ushort4 o;
    o.x = f2bf(v.x); o.y = f2bf(v.y); o.z = f2bf(v.z); o.w = f2bf(v.w);
    *(ushort4*)(Wbf + idx) = o;
}

// h[n][o] = relu(feats[n][:].W[o][:] + b[o]) via bf16 MFMA.
// MLP-first design: per chunk each wave issues 16 global_load_lds DMAs (zero
// VGPR cost -> 16 KB in flight per wave, 128 KB per CU across the 2 co-resident
// blocks) and drains ONCE. 2 chunks total. Cross-block overlap hides drains;
// grid 391 fully co-resident (2 blocks/CU by 64 KB LDS) -> zero dispatch tail.
// h written as two fp16 column-planes [2][N][64] (pool working-set lever).
__global__ __launch_bounds__(256) void fc_mfma_kernel(
    const float* __restrict__ feats, const ushort* __restrict__ Wbf,
    const float* __restrict__ bias, __half* __restrict__ h, int N)
{
    __shared__ char lds[MT * KCH * 4];   // 64 KB fp32 chunk; reused for out-tile
    const int tid  = threadIdx.x;
    const int lane = tid & 63;
    const int wv   = tid >> 6;
    const int wm   = wv >> 1, wn = wv & 1;
    const int l15  = lane & 15, lq = lane >> 4;
    const int nb   = blockIdx.x * MT;

    f32x4 acc[4][4];
    #pragma unroll
    for (int mi = 0; mi < 4; ++mi)
        #pragma unroll
        for (int ni = 0; ni < 4; ++ni) acc[mi][ni] = (f32x4){0.f, 0.f, 0.f, 0.f};

    #pragma unroll
    for (int kc = 0; kc < 2; ++kc) {
        if (kc) __syncthreads();   // chunk-0 reads complete before overwrite

        // ---- stage: 16 DMAs/wave, each 1 KB = 2 rows x 512 B (32 units) ----
        // lane l: row half l>>5, unit u=l&31, source unit pre-XORed (row&7)
        // so linear LDS dest ends up read-swizzled (G4/m173).
        #pragma unroll
        for (int it = 0; it < 16; ++it) {
            const int row = wv * 32 + it * 2 + (lane >> 5);
            const int su  = (lane & 31) ^ (row & 7);
            int grow = nb + row; if (grow > N - 1) grow = N - 1;
            const float* src = feats + (size_t)grow * DIN + kc * KCH + su * 4;
            gload_lds16(src, lds + (wv * 32 + it * 2) * 512);
        }

        // ---- B fragments for this chunk (lands while DMA drains) ----
        bf16x8 breg[4][4];   // [j][ni]
        #pragma unroll
        for (int j = 0; j < 4; ++j)
            #pragma unroll
            for (int ni = 0; ni < 4; ++ni)
                breg[j][ni] = *(const bf16x8*)(
                    Wbf + (size_t)(wn * 64 + ni * 16 + l15) * DIN
                        + kc * KCH + j * 32 + lq * 8);

        __syncthreads();   // single drain for the whole chunk

        // ---- compute: 4 K-steps of 32; ds_read fp32 (swizzled) + cvt + MFMA ----
        #pragma unroll
        for (int j = 0; j < 4; ++j) {
            bf16x8 a[4];
            #pragma unroll
            for (int mi = 0; mi < 4; ++mi) {
                const int row = wm * 64 + mi * 16 + l15;
                const int X = row & 7;
                const int u0 = j * 8 + lq * 2;
                const f32x4 lo = *(const f32x4*)(lds + row * 512 + ((u0)     ^ X) * 16);
                const f32x4 hi = *(const f32x4*)(lds + row * 512 + ((u0 + 1) ^ X) * 16);
                a[mi] = cvt8(lo, hi);
            }
            #pragma unroll
            for (int mi = 0; mi < 4; ++mi)
                #pragma unroll
                for (int ni = 0; ni < 4; ++ni)
                    acc[mi][ni] = __builtin_amdgcn_mfma_f32_16x16x32_bf16(
                        a[mi], breg[j][ni], acc[mi][ni], 0, 0, 0);
        }
    }

    // ---- epilogue: bias+relu -> fp16 out-tile in LDS -> coalesced plane stores ----
    float bcol[4];
    #pragma unroll
    for (int ni = 0; ni < 4; ++ni) bcol[ni] = bias[wn * 64 + ni * 16 + l15];

    __syncthreads();   // A-tile reads done; reuse LDS for out-tile (32 KB)
    #pragma unroll
    for (int mi = 0; mi < 4; ++mi) {
        const int lrow0 = wm * 64 + mi * 16 + lq * 4;
        #pragma unroll
        for (int ni = 0; ni < 4; ++ni) {
            const int col = wn * 64 + ni * 16 + l15;
            #pragma unroll
            for (int r = 0; r < 4; ++r) {
                const float v = fmaxf(acc[mi][ni][r] + bcol[ni], 0.f);
                *(ushort*)(lds + (lrow0 + r) * 256 + col * 2) =
                    __half_as_ushort(__float2half_rn(v));
            }
        }
    }
    __syncthreads();

    // read back: thread t -> row t>>1, plane t&1; 128 B to plane (t&1)
    {
        const int lrow = tid >> 1, p = tid & 1;
        const int grow = nb + lrow;
        if (grow < N) {
            ushort* dst = (ushort*)h + (size_t)p * N * 64 + (size_t)grow * 64;
            #pragma unroll
            for (int i = 0; i < 8; ++i)
                *(bf16x8*)(dst + i * 8) =
                    *(const bf16x8*)(lds + lrow * 256 + p * 128 + i * 16);
        }
    }
}

// pooled[n][p*64..+63] = mean_k hplane_p[edge[n][k]][:]
// One pass per 6.4 MB plane (stream-serialized) -> halved gather working set;
// 8 lanes/node x 16 B = 128 B = one full L2 line per gathered row.
struct __align__(16) Half8 { __half2 a, b, c, d; };

__global__ __launch_bounds__(256) void pool_kernel(
    const __half* __restrict__ h, const int* __restrict__ edge,
    float* __restrict__ out, int N, int p)
{
    __shared__ int eLds[32 * KNBR];            // 4 KB

    const int tid = threadIdx.x;
    const int g   = tid >> 3;                  // node group 0..31
    const int l   = tid & 7;
    const int nb  = blockIdx.x * 32;

    const int* esrc = edge + (size_t)nb * KNBR;
    const int limit = (N - nb) * KNBR;
    #pragma unroll
    for (int i = 0; i < 4; ++i) {
        const int ei = tid + i * 256;
        eLds[ei] = (ei < limit) ? esrc[ei] : 0;
    }
    __syncthreads();

    const int node = nb + g;
    if (node >= N) return;

    const Half8* plane = (const Half8*)((const ushort*)h + (size_t)p * N * 64);
    const int* el = &eLds[g * KNBR];           // plane row = 8 Half8

    float4 acc0 = {0.f, 0.f, 0.f, 0.f};
    float4 acc1 = {0.f, 0.f, 0.f, 0.f};

    #pragma unroll
    for (int b = 0; b < 2; ++b) {
        Half8 v[16];
        #pragma unroll
        for (int k = 0; k < 16; ++k)
            v[k] = plane[(size_t)el[b * 16 + k] * 8 + l];
        #pragma unroll
        for (int k = 0; k < 16; ++k) {
            const float2 f0 = __half22float2(v[k].a);
            const float2 f1 = __half22float2(v[k].b);
            const float2 f2 = __half22float2(v[k].c);
            const float2 f3 = __half22float2(v[k].d);
            acc0.x += f0.x; acc0.y += f0.y; acc0.z += f1.x; acc0.w += f1.y;
            acc1.x += f2.x; acc1.y += f2.y; acc1.z += f3.x; acc1.w += f3.y;
        }
    }

    const float s = 1.0f / (float)KNBR;
    float4 r0, r1;
    r0.x = acc0.x * s; r0.y = acc0.y * s; r0.z = acc0.z * s; r0.w = acc0.w * s;
    r1.x = acc1.x * s; r1.y = acc1.y * s; r1.z = acc1.z * s; r1.w = acc1.w * s;

    float4* op = (float4*)(out + (size_t)node * DOUT + p * 64 + l * 8);
    op[0] = r0; op[1] = r1;
}

extern "C" void kernel_launch(void* const* d_in, const int* in_sizes, int n_in,
                              void* d_out, int out_size, void* d_ws, size_t ws_size,
                              hipStream_t stream) {
    // dict order: ids, feats, W, b, edge_dict, G, ite
    const float* feats = (const float*)d_in[1];
    const float* W     = (const float*)d_in[2];
    const float* bias  = (const float*)d_in[3];
    const int*   edge  = (const int*)d_in[4];
    float* out = (float*)d_out;

    const int N = in_sizes[1] / DIN;            // 50000
    __half* h   = (__half*)d_ws;                // 2 planes x N x 64 fp16 = 12.8 MB
    ushort* Wbf = (ushort*)((char*)d_ws + (size_t)2 * N * 64 * sizeof(__half));

    wconv_kernel<<<(DOUT * DIN) / 1024, 256, 0, stream>>>(W, Wbf);
    fc_mfma_kernel<<<(N + MT - 1) / MT, 256, 0, stream>>>(feats, Wbf, bias, h, N);
    const int pblocks = (N + 31) / 32;          // 1563
    pool_kernel<<<pblocks, 256, 0, stream>>>(h, edge, out, N, 0);
    pool_kernel<<<pblocks, 256, 0, stream>>>(h, edge, out, N, 1);
}

// Round 16
// 63.396 us; speedup vs baseline: 1.2480x; 1.0741x over previous
//
#include <hip/hip_runtime.h>
#include <hip/hip_fp16.h>

#define DIN 256
#define DOUT 128
#define KNBR 32
#define MT 128        // M-tile rows per FC block; grid 391

typedef __attribute__((ext_vector_type(4))) float f32x4;
typedef __attribute__((ext_vector_type(8))) short bf16x8;

// packed f32x2 -> bf16x2 (RNE); no builtin on gfx950 -> inline asm
static __device__ __forceinline__ uint cvtpk(float lo, float hi) {
    uint r;
    asm("v_cvt_pk_bf16_f32 %0, %1, %2" : "=v"(r) : "v"(lo), "v"(hi));
    return r;
}

static __device__ __forceinline__ bf16x8 cvt8(const f32x4 lo, const f32x4 hi) {
    uint4 u;
    u.x = cvtpk(lo.x, lo.y); u.y = cvtpk(lo.z, lo.w);
    u.z = cvtpk(hi.x, hi.y); u.w = cvtpk(hi.z, hi.w);
    union { uint4 q; bf16x8 v; } cv; cv.q = u;
    return cv.v;
}

// h[n][o] = relu(feats[n][:].W[o][:] + b[o]) via bf16 MFMA.
// Fabric-bound (~26 us incl. overhead): feats re-fetch through L3/fabric at
// ~3.3 TB/s after the harness's 268 MB poison fills evict L3 -- ten kernel
// structures (reg/DMA staged, all tiles/occupancies, barrier-free) all land
// 26-31 us. This is the r13/r14 version: reg-staged A, swizzled LDS, pure
// ds_read+MFMA K-loop, W fp32 direct (no wconv), plane-wise coalesced h out.
__global__ __launch_bounds__(256) void fc_mfma_kernel(
    const float* __restrict__ feats, const float* __restrict__ W,
    const float* __restrict__ bias, __half* __restrict__ h, int N)
{
    __shared__ char lds[MT * DIN * 2];   // 64 KB: bf16 A-tile, then out-tile
    const int tid  = threadIdx.x;
    const int lane = tid & 63;
    const int wv   = tid >> 6;
    const int wm   = wv >> 1, wn = wv & 1;
    const int l15  = lane & 15, lq = lane >> 4;
    const int nb   = blockIdx.x * MT;

    // ---- stage A: 128 rows x 32 units (16B bf16 = 8 cols); 16 units/thread ----
    #pragma unroll
    for (int i = 0; i < 16; ++i) {
        const int u    = i * 256 + tid;
        const int row  = u >> 5;
        const int unit = u & 31;
        int grow = nb + row; if (grow > N - 1) grow = N - 1;
        const float* src = feats + (size_t)grow * DIN + unit * 8;
        const f32x4 lo = *(const f32x4*)(src);
        const f32x4 hi = *(const f32x4*)(src + 4);
        *(bf16x8*)(lds + row * 512 + (unit ^ (row & 7)) * 16) = cvt8(lo, hi);
    }
    __syncthreads();

    // ---- K loop: pure ds_read + MFMA; B from L2-resident fp32 W (cvt in reg) ----
    f32x4 acc[4][4];
    #pragma unroll
    for (int mi = 0; mi < 4; ++mi)
        #pragma unroll
        for (int ni = 0; ni < 4; ++ni) acc[mi][ni] = (f32x4){0.f, 0.f, 0.f, 0.f};

    #pragma unroll
    for (int ks = 0; ks < 8; ++ks) {
        bf16x8 breg[4];
        #pragma unroll
        for (int ni = 0; ni < 4; ++ni) {
            const float* wr = W + (size_t)(wn * 64 + ni * 16 + l15) * DIN
                                + ks * 32 + lq * 8;
            breg[ni] = cvt8(*(const f32x4*)wr, *(const f32x4*)(wr + 4));
        }
        bf16x8 a[4];
        #pragma unroll
        for (int mi = 0; mi < 4; ++mi) {
            const int row = wm * 64 + mi * 16 + l15;
            a[mi] = *(const bf16x8*)(
                lds + row * 512 + ((ks * 4 + lq) ^ (row & 7)) * 16);
        }
        #pragma unroll
        for (int mi = 0; mi < 4; ++mi)
            #pragma unroll
            for (int ni = 0; ni < 4; ++ni)
                acc[mi][ni] = __builtin_amdgcn_mfma_f32_16x16x32_bf16(
                    a[mi], breg[ni], acc[mi][ni], 0, 0, 0);
    }

    // ---- epilogue: bias+relu -> fp16 out-tile in LDS -> coalesced plane stores ----
    float bcol[4];
    #pragma unroll
    for (int ni = 0; ni < 4; ++ni) bcol[ni] = bias[wn * 64 + ni * 16 + l15];

    __syncthreads();   // A-tile reads done; reuse LDS for out-tile (32 KB)
    #pragma unroll
    for (int mi = 0; mi < 4; ++mi) {
        const int lrow0 = wm * 64 + mi * 16 + lq * 4;
        #pragma unroll
        for (int ni = 0; ni < 4; ++ni) {
            const int col = wn * 64 + ni * 16 + l15;
            #pragma unroll
            for (int r = 0; r < 4; ++r) {
                const float v = fmaxf(acc[mi][ni][r] + bcol[ni], 0.f);
                *(ushort*)(lds + (lrow0 + r) * 256 + col * 2) =
                    __half_as_ushort(__float2half_rn(v));
            }
        }
    }
    __syncthreads();

    // read back: thread t -> row t>>1, plane t&1; 128 B to plane (t&1)
    {
        const int lrow = tid >> 1, p = tid & 1;
        const int grow = nb + lrow;
        if (grow < N) {
            ushort* dst = (ushort*)h + (size_t)p * N * 64 + (size_t)grow * 64;
            #pragma unroll
            for (int i = 0; i < 8; ++i)
                *(bf16x8*)(dst + i * 8) =
                    *(const bf16x8*)(lds + lrow * 256 + p * 128 + i * 16);
        }
    }
}

// pooled[n][p*64..+63] = mean_k hplane_p[edge[n][k]][:]
// SINGLE launch, XCD-pinned planes: plane = (blockIdx&7)>>2 under round-robin
// block->XCD dispatch => XCDs 0-3 gather only plane 0, XCDs 4-7 only plane 1.
// Per-XCD L2 working set stays 6.4 MB (same as two serialized passes) but with
// no inter-pass bubble and one launch fewer. 8 lanes/node x 16 B = 128 B = one
// full L2 line per gathered row; 16-deep explicit load batches.
struct __align__(16) Half8 { __half2 a, b, c, d; };

__global__ __launch_bounds__(256) void pool_kernel(
    const __half* __restrict__ h, const int* __restrict__ edge,
    float* __restrict__ out, int N, int nchunks)
{
    const int bi    = blockIdx.x;
    const int p     = (bi & 7) >> 2;                 // plane, fixed per XCD
    const int chunk = ((bi >> 3) << 2) | (bi & 3);   // chunk within plane
    if (chunk >= nchunks) return;                    // block-uniform guard
    const int nb = chunk * 32;

    __shared__ int eLds[32 * KNBR];            // 4 KB
    const int tid = threadIdx.x;

    // stage this chunk's 1024 edge indices (coalesced, guarded)
    const int* esrc = edge + (size_t)nb * KNBR;
    const int limit = (N - nb) * KNBR;
    #pragma unroll
    for (int i = 0; i < 4; ++i) {
        const int ei = tid + i * 256;
        eLds[ei] = (ei < limit) ? esrc[ei] : 0;
    }
    __syncthreads();

    const int g = tid >> 3;                    // local node 0..31
    const int l = tid & 7;
    const int node = nb + g;
    if (node >= N) return;

    const Half8* plane = (const Half8*)((const ushort*)h + (size_t)p * N * 64);
    const int* el = &eLds[g * KNBR];           // plane row = 8 Half8 = 128 B

    float4 acc0 = {0.f, 0.f, 0.f, 0.f};
    float4 acc1 = {0.f, 0.f, 0.f, 0.f};

    #pragma unroll
    for (int b = 0; b < 2; ++b) {
        Half8 v[16];
        #pragma unroll
        for (int k = 0; k < 16; ++k)
            v[k] = plane[(size_t)el[b * 16 + k] * 8 + l];
        #pragma unroll
        for (int k = 0; k < 16; ++k) {
            const float2 f0 = __half22float2(v[k].a);
            const float2 f1 = __half22float2(v[k].b);
            const float2 f2 = __half22float2(v[k].c);
            const float2 f3 = __half22float2(v[k].d);
            acc0.x += f0.x; acc0.y += f0.y; acc0.z += f1.x; acc0.w += f1.y;
            acc1.x += f2.x; acc1.y += f2.y; acc1.z += f3.x; acc1.w += f3.y;
        }
    }

    const float s = 1.0f / (float)KNBR;
    float4 r0, r1;
    r0.x = acc0.x * s; r0.y = acc0.y * s; r0.z = acc0.z * s; r0.w = acc0.w * s;
    r1.x = acc1.x * s; r1.y = acc1.y * s; r1.z = acc1.z * s; r1.w = acc1.w * s;

    float4* op = (float4*)(out + (size_t)node * DOUT + p * 64 + l * 8);
    op[0] = r0; op[1] = r1;
}

extern "C" void kernel_launch(void* const* d_in, const int* in_sizes, int n_in,
                              void* d_out, int out_size, void* d_ws, size_t ws_size,
                              hipStream_t stream) {
    // dict order: ids, feats, W, b, edge_dict, G, ite
    const float* feats = (const float*)d_in[1];
    const float* W     = (const float*)d_in[2];
    const float* bias  = (const float*)d_in[3];
    const int*   edge  = (const int*)d_in[4];
    float* out = (float*)d_out;

    const int N = in_sizes[1] / DIN;            // 50000
    __half* h   = (__half*)d_ws;                // 2 planes x N x 64 fp16 = 12.8 MB

    fc_mfma_kernel<<<(N + MT - 1) / MT, 256, 0, stream>>>(feats, W, bias, h, N);

    const int nchunks = (N + 31) / 32;          // 1563 chunks per plane
    // grid covers 2 planes x nchunks with per-XCD plane pinning; round up so
    // both (bi&7)-halves reach nchunks, guard handles the spares.
    const int grid = ((nchunks + 3) / 4) * 8;   // 3128
    pool_kernel<<<grid, 256, 0, stream>>>(h, edge, out, N, nchunks);
}